// Round 1
// baseline (49.944 us; speedup 1.0000x reference)
//
#include <hip/hip_runtime.h>
#include <stdint.h>

#define BATCH 32
#define NA    8400
#define NL    80
#define NH    256
#define NK    300

// output float offsets (concatenated return order)
#define OUT0 0                       // init_reference_points (32,300,4)
#define OUT1 38400                   // target                (32,300,256)
#define OUT2 2496000                 // enc_topk_logits       (32,300,80)
#define OUT3 3264000                 // enc_topk_bboxes       (32,300,4)

__device__ __forceinline__ unsigned mapf(float f) {
    unsigned u = __float_as_uint(f);
    return (u & 0x80000000u) ? ~u : (u | 0x80000000u);
}

// Kernel 1: per-(b,a) max over L=80, store monotone-mapped u32.
// 4 threads per row, float4 loads, 64 rows per 256-thread block.
__global__ __launch_bounds__(256) void cls_max_kernel(const float* __restrict__ cls,
                                                      unsigned* __restrict__ out_u) {
    int tid = threadIdx.x;
    int row = blockIdx.x * 64 + (tid >> 2);
    int sub = tid & 3;
    if (row >= BATCH * NA) return;
    const float4* p = (const float4*)(cls + (size_t)row * NL);
    float m = -3.4e38f;
#pragma unroll
    for (int q = 0; q < 5; ++q) {
        float4 v = p[sub + q * 4];
        m = fmaxf(m, fmaxf(fmaxf(v.x, v.y), fmaxf(v.z, v.w)));
    }
    m = fmaxf(m, __shfl_xor(m, 1));
    m = fmaxf(m, __shfl_xor(m, 2));
    if (sub == 0) out_u[row] = mapf(m);
}

// Kernel 2: exact top-300 per batch. One block per batch, 1024 threads.
__global__ __launch_bounds__(1024) void topk_kernel(const unsigned* __restrict__ u_in,
                                                    int* __restrict__ topk_idx) {
    __shared__ unsigned su[NA];
    __shared__ unsigned hist[256];
    __shared__ unsigned long long keys[512];
    __shared__ unsigned s_bin, s_cumAbove, s_count;

    int tid = threadIdx.x;
    int b   = blockIdx.x;
    const unsigned* ub = u_in + b * NA;
    for (int i = tid; i < NA; i += 1024) su[i] = ub[i];
    if (tid < 512) keys[tid] = ~0ULL;   // pad: sorts to the end (ascending)
    if (tid == 0) s_count = 0;
    __syncthreads();

    // 4-round radix select: find exact u-value of rank-(NK-1) element
    unsigned prefix = 0, pmask = 0;
    int kRem = NK;
    for (int shift = 24; shift >= 0; shift -= 8) {
        if (tid < 256) hist[tid] = 0;
        __syncthreads();
        for (int i = tid; i < NA; i += 1024) {
            unsigned v = su[i];
            if ((v & pmask) == prefix) atomicAdd(&hist[(v >> shift) & 255u], 1u);
        }
        __syncthreads();
        // in-place suffix sum over 256 bins
        for (int d = 1; d < 256; d <<= 1) {
            unsigned v = 0;
            if (tid < 256 && tid + d < 256) v = hist[tid + d];
            __syncthreads();
            if (tid < 256) hist[tid] += v;
            __syncthreads();
        }
        if (tid < 256) {
            unsigned ge = hist[tid];                       // count bin >= tid
            unsigned gt = (tid == 255) ? 0u : hist[tid + 1]; // count bin > tid
            if (ge >= (unsigned)kRem && gt < (unsigned)kRem) {
                s_bin = (unsigned)tid;
                s_cumAbove = gt;
            }
        }
        __syncthreads();
        kRem  -= (int)s_cumAbove;
        prefix |= (s_bin << shift);
        pmask  |= (255u << shift);
        __syncthreads();
    }

    // collect candidates u >= threshold (exactly NK for distinct values)
    for (int i = tid; i < NA; i += 1024) {
        unsigned v = su[i];
        if (v >= prefix) {
            unsigned pos = atomicAdd(&s_count, 1u);
            if (pos < 512) keys[pos] = ((unsigned long long)(~v) << 32) | (unsigned)i;
        }
    }
    __syncthreads();

    // bitonic ascending sort of 512 keys: (~u, idx) asc == (u desc, idx asc)
    for (int k = 2; k <= 512; k <<= 1) {
        for (int j = k >> 1; j > 0; j >>= 1) {
            int i = tid;
            if (i < 512) {
                int ixj = i ^ j;
                if (ixj > i) {
                    unsigned long long a = keys[i], c = keys[ixj];
                    bool up = ((i & k) == 0);
                    if ((a > c) == up) { keys[i] = c; keys[ixj] = a; }
                }
            }
            __syncthreads();
        }
    }
    if (tid < NK) topk_idx[b * NK + tid] = (int)(keys[tid] & 0xFFFFFFFFull);
}

// Kernel 3: gathers + sigmoid. One 64-lane wave per (b,q).
__global__ __launch_bounds__(256) void gather_kernel(const float* __restrict__ cls,
                                                     const float* __restrict__ coord,
                                                     const float* __restrict__ mem,
                                                     const int* __restrict__ topk_idx,
                                                     float* __restrict__ out) {
    int wid  = blockIdx.x * 4 + (threadIdx.x >> 6);
    int lane = threadIdx.x & 63;
    if (wid >= BATCH * NK) return;
    int b = wid / NK;
    int q = wid - b * NK;
    int idx = topk_idx[b * NK + q];
    size_t srow = (size_t)b * NA + (size_t)idx;
    size_t drow = (size_t)b * NK + (size_t)q;

    // target: 256 floats, one float4 per lane
    const float4* msrc = (const float4*)(mem + srow * NH);
    float4*       mdst = (float4*)(out + OUT1 + drow * NH);
    mdst[lane] = msrc[lane];

    // logits: 80 floats = 20 float4
    if (lane < 20) {
        const float4* lsrc = (const float4*)(cls + srow * NL);
        float4*       ldst = (float4*)(out + OUT2 + drow * NL);
        ldst[lane] = lsrc[lane];
    }

    // coords (raw) + sigmoid
    if (lane == 0) {
        float4 c = ((const float4*)(coord + srow * 4))[0];
        ((float4*)(out + OUT0 + drow * 4))[0] = c;
        float4 s;
        s.x = 1.0f / (1.0f + __expf(-c.x));
        s.y = 1.0f / (1.0f + __expf(-c.y));
        s.z = 1.0f / (1.0f + __expf(-c.z));
        s.w = 1.0f / (1.0f + __expf(-c.w));
        ((float4*)(out + OUT3 + drow * 4))[0] = s;
    }
}

extern "C" void kernel_launch(void* const* d_in, const int* in_sizes, int n_in,
                              void* d_out, int out_size, void* d_ws, size_t ws_size,
                              hipStream_t stream) {
    const float* cls   = (const float*)d_in[0]; // (32,8400,80)
    const float* coord = (const float*)d_in[1]; // (32,8400,4)
    const float* mem   = (const float*)d_in[2]; // (32,8400,256)
    // d_in[3] (sources_last_element) unused by the reference

    unsigned* ws_u = (unsigned*)d_ws;                                  // 32*8400 u32
    int*      topk = (int*)((char*)d_ws + (size_t)BATCH * NA * 4);     // 32*300 i32
    float*    out  = (float*)d_out;

    cls_max_kernel<<<(BATCH * NA) / 64, 256, 0, stream>>>(cls, ws_u);
    topk_kernel<<<BATCH, 1024, 0, stream>>>(ws_u, topk);
    gather_kernel<<<(BATCH * NK) / 4, 256, 0, stream>>>(cls, coord, mem, topk, out);
}